// Round 13
// baseline (113.118 us; speedup 1.0000x reference)
//
#include <hip/hip_runtime.h>
#include <hip/hip_bf16.h>

#define DIM 256
#define NHEADS 8
#define HDIM 32
#define Bq 4
#define Nq 4096   // 64*64
#define Nu 1024   // 32*32

typedef __attribute__((ext_vector_type(8))) short bf16x8;
typedef __attribute__((ext_vector_type(16))) float f32x16;
typedef __attribute__((ext_vector_type(4))) unsigned short us4;

__device__ __forceinline__ ushort f2bf(float x) {
    union { float f; unsigned u; } v; v.f = x;
    unsigned r = v.u + 0x7fffu + ((v.u >> 16) & 1u);
    return (ushort)(r >> 16);
}
__device__ __forceinline__ float bf2f(ushort u) {
    union { unsigned u; float f; } v; v.u = ((unsigned)u) << 16;
    return v.f;
}
__device__ __forceinline__ float bfu2f(unsigned lo16shifted) {
    union { unsigned u; float f; } v; v.u = lo16shifted;
    return v.f;
}

// ---------------------------------------------------------------------------
// prepro: weight casts only.  grid 512 x 256 threads.
// ---------------------------------------------------------------------------
__global__ __launch_bounds__(256) void prepro(
    const float* __restrict__ Wq, ushort* __restrict__ Oq,
    const float* __restrict__ Wkv, ushort* __restrict__ Okv,
    const float* __restrict__ Wp, ushort* __restrict__ Oph, ushort* __restrict__ Opl)
{
    const int i = blockIdx.x * 256 + threadIdx.x;
    if (i < 65536) {
        Oq[i] = f2bf(Wq[i]);
        float w = Wp[i];
        ushort h = f2bf(w);
        Oph[i] = h;
        Opl[i] = f2bf(w - bf2f(h));
    }
    Okv[i] = f2bf(Wkv[i]);
}

// ---------------------------------------------------------------------------
// qkv (fused transpose + GEMM): blocks [0,512): Q (128 n-blocks x 4 b);
// [512,768): KV (32 n x 2 oh x 4 b).
// Stages a [32 n][256 c] bf16 tile of fp32 input through swizzled LDS
// (in-register cvt_pk transpose), then each wave computes 64 output rows:
// Q: heads 2w,2w+1; KV: head oh*4+w's K (transposed out) + V (direct out).
// ---------------------------------------------------------------------------
__global__ __launch_bounds__(256, 4) void qkv_mfma(
    const ushort* __restrict__ Wqb, const float* __restrict__ x,
    const float* __restrict__ q_scale, const float* __restrict__ q_bias, float qmult,
    const ushort* __restrict__ Wkvb, const float* __restrict__ upper,
    const float* __restrict__ kv_scale, const float* __restrict__ kv_bias,
    ushort* __restrict__ Qb, ushort* __restrict__ Kb, ushort* __restrict__ Vb)
{
    __shared__ __align__(16) ushort S[32 * 256];   // 16 KB, swizzled [n][c]
    const int id = blockIdx.x;
    const int tid = threadIdx.x;

    const float* In; int N, n0, b, oh; bool isQ;
    if (id < 512) {
        isQ = true; In = x; N = 4096;
        n0 = (id & 127) * 32; b = id >> 7; oh = 0;
    } else {
        int q = id - 512;
        isQ = false; In = upper; N = 1024;
        n0 = (q & 31) * 32; oh = (q >> 5) & 1; b = q >> 6;
    }

    // ---- stage S[n][c] = bf16(In[c][n]) ----
    {
        const int n4 = (tid & 7) * 4, c8 = (tid >> 3) * 8;
        const float* ip = In + ((size_t)b * 256 + c8) * N + n0 + n4;
        unsigned ow[4][4];                 // [local n j][c-pair rp]
        #pragma unroll
        for (int rp = 0; rp < 4; ++rp) {
            float4 f0 = *(const float4*)(ip + (size_t)(2 * rp) * N);
            float4 f1 = *(const float4*)(ip + (size_t)(2 * rp + 1) * N);
            asm("v_cvt_pk_bf16_f32 %0, %1, %2" : "=v"(ow[0][rp]) : "v"(f0.x), "v"(f1.x));
            asm("v_cvt_pk_bf16_f32 %0, %1, %2" : "=v"(ow[1][rp]) : "v"(f0.y), "v"(f1.y));
            asm("v_cvt_pk_bf16_f32 %0, %1, %2" : "=v"(ow[2][rp]) : "v"(f0.z), "v"(f1.z));
            asm("v_cvt_pk_bf16_f32 %0, %1, %2" : "=v"(ow[3][rp]) : "v"(f0.w), "v"(f1.w));
        }
        #pragma unroll
        for (int j = 0; j < 4; ++j) {
            const int n = n4 + j;
            const int slot = ((c8 >> 3) ^ (n & 15)) & 31;
            *(uint4*)(&S[n * 256 + (slot << 3)]) = *(const uint4*)&ow[j][0];
        }
    }
    __syncthreads();

    const int w = tid >> 6, l = tid & 63;
    const int l31 = l & 31, hi = l >> 5;
    const int nsw = l31 & 15;
    const ushort* Srow = &S[l31 * 256];

    if (isQ) {
        const ushort* w0 = Wqb + (size_t)(w * 64 + l31) * 256 + hi * 8;
        const ushort* w1 = w0 + (size_t)32 * 256;
        f32x16 acc0 = {}, acc1 = {};
        #pragma unroll 8
        for (int kk = 0; kk < 256; kk += 16) {
            const int slot = (((kk >> 3) + hi) ^ nsw) & 31;
            bf16x8 av = *(const bf16x8*)(Srow + (slot << 3));
            bf16x8 h0 = *(const bf16x8*)(w0 + kk);
            bf16x8 h1 = *(const bf16x8*)(w1 + kk);
            acc0 = __builtin_amdgcn_mfma_f32_32x32x16_bf16(av, h0, acc0, 0, 0, 0);
            acc1 = __builtin_amdgcn_mfma_f32_32x32x16_bf16(av, h1, acc1, 0, 0, 0);
        }
        #pragma unroll
        for (int t = 0; t < 2; ++t) {
            const f32x16 a = t ? acc1 : acc0;
            const int orow = w * 64 + t * 32 + l31;
            const float sc = q_scale[orow] * qmult;
            const float bi = q_bias[orow] * qmult;
            const int bh = b * 8 + 2 * w + t;
            ushort* Oa = Qb + ((size_t)bh * 4096) * 32 + l31;
            #pragma unroll
            for (int r = 0; r < 16; ++r) {
                const int dn = (r & 3) + 8 * (r >> 2) + 4 * hi;
                Oa[(size_t)(n0 + dn) * 32] = f2bf(a[r] * sc + bi);
            }
        }
    } else {
        const int h = oh * 4 + w;
        const ushort* wk = Wkvb + (size_t)(h * 64 + l31) * 256 + hi * 8;
        const ushort* wv = wk + (size_t)32 * 256;
        f32x16 accK = {}, accV = {};
        #pragma unroll 8
        for (int kk = 0; kk < 256; kk += 16) {
            const int slot = (((kk >> 3) + hi) ^ nsw) & 31;
            bf16x8 av = *(const bf16x8*)(Srow + (slot << 3));
            bf16x8 k0 = *(const bf16x8*)(wk + kk);
            bf16x8 v0 = *(const bf16x8*)(wv + kk);
            accK = __builtin_amdgcn_mfma_f32_32x32x16_bf16(av, k0, accK, 0, 0, 0);
            accV = __builtin_amdgcn_mfma_f32_32x32x16_bf16(v0, av, accV, 0, 0, 0);
        }
        const int bh = b * 8 + h;
        {
            const float sc = kv_scale[h * 64 + l31];
            const float bi = kv_bias[h * 64 + l31];
            ushort* Oa = Kb + ((size_t)bh * 1024) * 32 + l31;
            #pragma unroll
            for (int r = 0; r < 16; ++r) {
                const int dn = (r & 3) + 8 * (r >> 2) + 4 * hi;
                Oa[(size_t)(n0 + dn) * 32] = f2bf(accK[r] * sc + bi);
            }
        }
        {
            ushort* Ob = Vb + (size_t)bh * 32 * 1024;
            #pragma unroll
            for (int r = 0; r < 16; ++r) {
                const int dr = (r & 3) + 8 * (r >> 2) + 4 * hi;
                const float sc = kv_scale[h * 64 + 32 + dr];
                const float bi = kv_bias[h * 64 + 32 + dr];
                Ob[(size_t)dr * 1024 + n0 + l31] = f2bf(accV[r] * sc + bi);
            }
        }
    }
}

// ---------------------------------------------------------------------------
// attn_dw (merged): blocks [0,1024): flash attention (bf16 output);
// [1024,2048): depthwise 7x7 -> 32x32 bf16 field (upsample lives in proj).
// __launch_bounds__(256, 8): 8 blocks/CU (VGPR 52 <= 64, LDS 8x16KB=128KB)
// -> entire 2048-block grid co-resident; attn latency hidden by 32 waves/CU
// and attn/dw mix per CU (XCD-balanced, unlike the R11 parity trap).
// FROZEN: attention inner loop is the R6-proven structure — do not modify.
// ---------------------------------------------------------------------------
__global__ __launch_bounds__(256, 8) void attn_dw(
    const ushort* __restrict__ Qb, const ushort* __restrict__ Kt,
    const ushort* __restrict__ Vb, ushort* __restrict__ ao,
    const float* __restrict__ Wpe, const float* __restrict__ pe_scale,
    const float* __restrict__ pe_bias, ushort* __restrict__ vh)
{
    __shared__ __align__(16) unsigned char smem[16384];
    const int tid = threadIdx.x;

    if (blockIdx.x < 1024) {
        // ---- attention ----
        const int w = tid >> 6, l = tid & 63;
        const int l31 = l & 31, hi = l >> 5;
        const int lid = blockIdx.x;
        const int j = lid >> 3;
        const int bh = (lid & 7) * 4 + (j >> 5);
        const int qbase = (j & 31) * 128 + w * 32;

        unsigned char (*ldsbuf)[8192] = (unsigned char(*)[8192])smem;

        const ushort* Qp = Qb + ((size_t)bh * 4096 + qbase) * 32;
        const unsigned char* Kg = (const unsigned char*)(Kt + (size_t)bh * 1024 * 32);
        const unsigned char* Vg = (const unsigned char*)(Vb + (size_t)bh * 32 * 1024);

        const bf16x8 qb0 = *(const bf16x8*)(Qp + (size_t)l31 * 32 + hi * 8);
        const bf16x8 qb1 = *(const bf16x8*)(Qp + (size_t)l31 * 32 + 16 + hi * 8);

        const int kr = tid >> 2, kc = tid & 3;
        const int vd = tid >> 3, vc = tid & 7;
        const int kwr = (kr * 64 + kc * 16) ^ ((kr & 7) << 4);
        const int vwr = vd * 128 + ((vc ^ (vd & 7)) << 4);

        f32x16 acc = {};
        float l_run = 0.f;

        uint4 kreg = *(const uint4*)(Kg + kr * 64 + kc * 16);
        uint4 vreg = *(const uint4*)(Vg + vd * 2048 + vc * 16);
        *(uint4*)(&ldsbuf[0][kwr]) = kreg;
        *(uint4*)(&ldsbuf[0][4096 + vwr]) = vreg;
        __syncthreads();

        for (int ph = 0; ph < 16; ++ph) {
            const int cur = ph & 1;
            if (ph < 15) {
                const size_t koff = (size_t)(ph + 1) * 4096;
                const int    voff = (ph + 1) * 128;
                kreg = *(const uint4*)(Kg + koff + kr * 64 + kc * 16);
                vreg = *(const uint4*)(Vg + (size_t)vd * 2048 + voff + vc * 16);
            }
            const unsigned char* Kl = &ldsbuf[cur][0];
            const unsigned char* Vl = &ldsbuf[cur][4096];

            #pragma unroll
            for (int s = 0; s < 2; ++s) {
                const int r = s * 32 + l31;
                bf16x8 ka0 = *(const bf16x8*)(Kl + ((r * 64 + hi * 16) ^ ((r & 7) << 4)));
                bf16x8 ka1 = *(const bf16x8*)(Kl + ((r * 64 + 32 + hi * 16) ^ ((r & 7) << 4)));
                bf16x8 va0 = *(const bf16x8*)(Vl + l31 * 128 + (((s * 4 + hi)     ^ (l31 & 7)) << 4));
                bf16x8 va1 = *(const bf16x8*)(Vl + l31 * 128 + (((s * 4 + 2 + hi) ^ (l31 & 7)) << 4));

                f32x16 sv = {};
                sv = __builtin_amdgcn_mfma_f32_32x32x16_bf16(ka0, qb0, sv, 0, 0, 0);
                sv = __builtin_amdgcn_mfma_f32_32x32x16_bf16(ka1, qb1, sv, 0, 0, 0);

                float p[16];
                #pragma unroll
                for (int r2 = 0; r2 < 16; ++r2) p[r2] = __builtin_amdgcn_exp2f(sv[r2]);
                l_run += (((p[0] + p[1]) + (p[2] + p[3])) + ((p[4] + p[5]) + (p[6] + p[7])))
                       + (((p[8] + p[9]) + (p[10] + p[11])) + ((p[12] + p[13]) + (p[14] + p[15])));

                int c[8];
                #pragma unroll
                for (int i = 0; i < 8; ++i)
                    asm("v_cvt_pk_bf16_f32 %0, %1, %2" : "=v"(c[i]) : "v"(p[2 * i]), "v"(p[2 * i + 1]));
                asm("v_permlane32_swap_b32 %0, %1" : "+v"(c[0]), "+v"(c[2]));
                asm("v_permlane32_swap_b32 %0, %1" : "+v"(c[1]), "+v"(c[3]));
                asm("v_permlane32_swap_b32 %0, %1" : "+v"(c[4]), "+v"(c[6]));
                asm("v_permlane32_swap_b32 %0, %1" : "+v"(c[5]), "+v"(c[7]));

                union { int i[4]; bf16x8 v; } b0u, b1u;
                b0u.i[0] = c[0]; b0u.i[1] = c[1]; b0u.i[2] = c[2]; b0u.i[3] = c[3];
                b1u.i[0] = c[4]; b1u.i[1] = c[5]; b1u.i[2] = c[6]; b1u.i[3] = c[7];

                acc = __builtin_amdgcn_mfma_f32_32x32x16_bf16(va0, b0u.v, acc, 0, 0, 0);
                acc = __builtin_amdgcn_mfma_f32_32x32x16_bf16(va1, b1u.v, acc, 0, 0, 0);
            }

            if (ph < 15) {
                const int nxt = cur ^ 1;
                *(uint4*)(&ldsbuf[nxt][kwr]) = kreg;
                *(uint4*)(&ldsbuf[nxt][4096 + vwr]) = vreg;
            }
            __syncthreads();
        }

        l_run += __shfl_xor(l_run, 32);
        float inv = 1.0f / l_run;

        ushort* aob = ao + ((size_t)(bh >> 3) * 256 + (bh & 7) * 32) * 4096 + qbase + l31;
        #pragma unroll
        for (int r = 0; r < 16; ++r) {
            const int d = (r & 3) + 8 * (r >> 2) + 4 * hi;
            aob[(size_t)d * 4096] = f2bf(acc[r] * inv);
        }
    } else {
        // ---- depthwise 7x7 (32x32 bf16 output; upsample in proj) ----
        const int bc = blockIdx.x - 1024;
        const int b = bc >> 8, c = bc & 255;
        const ushort* vp = Vb + ((size_t)(b * 8 + (c >> 5)) * 32 + (c & 31)) * 1024;

        float* t  = (float*)smem;               // 38*38*4 = 5776 B
        float* wl = (float*)(smem + 5776);      // 196 B

        for (int i = tid; i < 38 * 38; i += 256) {
            int yy = i / 38 - 3, xx = i % 38 - 3;
            t[i] = (yy >= 0 && yy < 32 && xx >= 0 && xx < 32) ? bf2f(vp[yy * 32 + xx]) : 0.f;
        }
        if (tid < 49) wl[tid] = Wpe[(size_t)c * 49 + tid];
        __syncthreads();

        const float sc = pe_scale[c], bi = pe_bias[c];
        ushort* op = vh + (size_t)bc * 1024;
        for (int i = tid; i < 1024; i += 256) {
            int y = i >> 5, x = i & 31;
            float s = 0.f;
            #pragma unroll
            for (int ky = 0; ky < 7; ++ky)
                #pragma unroll
                for (int kx = 0; kx < 7; ++kx)
                    s += t[(y + ky) * 38 + x + kx] * wl[ky * 7 + kx];
            op[i] = f2bf(s * sc + bi);
        }
    }
}

// ---------------------------------------------------------------------------
// Output projection (fused transpose+add+bilinear-upsample): 512-thread
// blocks, each covering ALL o=256 for one 64-wide n-tile (= one output row
// y = blockIdx.x).  Staging computes S[n][c] = ao[c][n] + bilinear(vh[c])
// inline (fx in {0.75,0.25} by x parity; fy uniform per block); vh is the
// bf16 32x32 pre-upsample field (unpacked to f32, lerped exactly).
// 8 waves: wave w -> o-quarter (w&3)*64, n-half (w>>2)*32.
// ---------------------------------------------------------------------------
__global__ __launch_bounds__(512, 2) void proj_mfma(
    const ushort* __restrict__ Whi, const ushort* __restrict__ Wlo,
    const ushort* __restrict__ ao, const ushort* __restrict__ vh,
    const float* __restrict__ scale, const float* __restrict__ bias,
    float* __restrict__ Out)
{
    __shared__ __align__(16) ushort S[64 * 256];   // 32 KB, swizzled [n][c]
    const int tid = threadIdx.x;
    const int b  = blockIdx.z;
    const int y  = blockIdx.x;             // output row; n0 = y*64
    const int n0 = y * 64;

    // ---- stage S[n][c] = ao[c][n] + vpe_bilinear(c, y, x=n-n0) ----
    {
        const int m  = tid & 15;           // x-quad: x = 4m + j, j=0..3
        const int c8 = (tid >> 4) * 8;     // 8 channels

        const int y0  = (y - 1) >> 1;
        const float fy = (y & 1) ? 0.25f : 0.75f;
        const float gy = 1.0f - fy;
        const int y0c = max(y0, 0), y1c = min(y0 + 1, 31);
        const int aIdx = max(m - 1, 0), cIdx = min(m + 1, 15);

        float sval[4][8];                  // [j][cc]
        #pragma unroll
        for (int cc = 0; cc < 8; ++cc) {
            const int ch = c8 + cc;
            const ushort* rowb = vh + (size_t)(b * 256 + ch) * 1024;
            const ushort* rT = rowb + y0c * 32;
            const ushort* rB = rowb + y1c * 32;
            // 2 bf16 per u32 load (4B aligned: even ushort indices)
            const unsigned ta  = *(const unsigned*)(rT + 2 * aIdx);
            const unsigned tb  = *(const unsigned*)(rT + 2 * m);
            const unsigned tc  = *(const unsigned*)(rT + 2 * cIdx);
            const unsigned ba  = *(const unsigned*)(rB + 2 * aIdx);
            const unsigned bb  = *(const unsigned*)(rB + 2 * m);
            const unsigned bc2 = *(const unsigned*)(rB + 2 * cIdx);
            const float tbx = bfu2f(tb << 16), tby = bfu2f(tb & 0xffff0000u);
            const float bbx = bfu2f(bb << 16), bby = bfu2f(bb & 0xffff0000u);
            const float t_m1 = (m == 0)  ? tbx : bfu2f(ta & 0xffff0000u); // pos 2m-1
            const float t_p2 = (m == 15) ? tby : bfu2f(tc << 16);         // pos 2m+2
            const float b_m1 = (m == 0)  ? bbx : bfu2f(ba & 0xffff0000u);
            const float b_p2 = (m == 15) ? bby : bfu2f(bc2 << 16);
            // horizontal lerps: j=0 fx=.75 (x0=2m-1), j=1 fx=.25 (x0=2m),
            // j=2 fx=.75 (x0=2m), j=3 fx=.25 (x0=2m+1)
            const float ht0 = 0.25f * t_m1 + 0.75f * tbx;
            const float ht1 = 0.75f * tbx + 0.25f * tby;
            const float ht2 = 0.25f * tbx + 0.75f * tby;
            const float ht3 = 0.75f * tby + 0.25f * t_p2;
            const float hb0 = 0.25f * b_m1 + 0.75f * bbx;
            const float hb1 = 0.75f * bbx + 0.25f * bby;
            const float hb2 = 0.25f * bbx + 0.75f * bby;
            const float hb3 = 0.75f * bby + 0.25f * b_p2;

            const ushort* ap = ao + (size_t)(b * 256 + ch) * 4096 + n0 + m * 4;
            uint2 av = *(const uint2*)ap;
            const float a0 = bfu2f(av.x << 16);
            const float a1 = bfu2f(av.x & 0xffff0000u);
            const float a2 = bfu2f(av.y << 16);
            const float a3 = bfu2f(av.y & 0xffff0000u);

            sval[0][cc] = a0 + (gy * ht0 + fy * hb0);
            sval[1][cc] = a1 + (gy * ht1 + fy * hb1);
            sval[2][cc] = a2 + (gy * ht2 + fy * hb2);
            sval[3][cc] = a3 + (gy * ht3 + fy * hb3);
        }

        #pragma unroll
        for (int j = 0; j < 4; ++j) {
            unsigned ow[4];
            #pragma unroll
            for (int rp = 0; rp < 4; ++rp)
                asm("v_cvt_pk_bf16_f32 %0, %1, %2"
                    : "=v"(ow[rp]) : "v"(sval[j][2 * rp]), "v"(sval[j][2 * rp + 1]));
            const int n = m * 4 + j;
            const int slot = (((c8 >> 3) ^ (n & 15)) & 31);
            *(uint4*)(&S[n * 256 + (slot << 3)]) = *(const uint4*)&ow[0];
        }
    }
    __syncthreads();

    // ---- GEMM ----
    const int w = tid >> 6, l = tid & 63;
    const int l31 = l & 31, hi = l >> 5;
    const int wo = w & 3, wn = w >> 2;     // o-quarter (64), n-half (32)
    const int ob = wo * 64;

    const ushort* wh0 = Whi + (size_t)(ob + l31) * 256 + hi * 8;
    const ushort* wh1 = wh0 + (size_t)32 * 256;
    const ushort* wl0 = Wlo + (size_t)(ob + l31) * 256 + hi * 8;
    const ushort* wl1 = wl0 + (size_t)32 * 256;

    const int nloc = wn * 32 + l31;
    const ushort* Srow = &S[nloc * 256];
    const int nsw = nloc & 15;

    f32x16 acc0 = {}, acc1 = {};           // acc0: o in [ob,ob+32), acc1: +32
    #pragma unroll 4
    for (int kk = 0; kk < 256; kk += 16) {
        const int slot = (((kk >> 3) + hi) ^ nsw) & 31;
        bf16x8 av = *(const bf16x8*)(Srow + (slot << 3));
        bf16x8 h0 = *(const bf16x8*)(wh0 + kk);
        bf16x8 h1 = *(const bf16x8*)(wh1 + kk);
        bf16x8 g0 = *(const bf16x8*)(wl0 + kk);
        bf16x8 g1 = *(const bf16x8*)(wl1 + kk);
        acc0 = __builtin_amdgcn_mfma_f32_32x32x16_bf16(h0, av, acc0, 0, 0, 0);
        acc1 = __builtin_amdgcn_mfma_f32_32x32x16_bf16(h1, av, acc1, 0, 0, 0);
        acc0 = __builtin_amdgcn_mfma_f32_32x32x16_bf16(g0, av, acc0, 0, 0, 0);
        acc1 = __builtin_amdgcn_mfma_f32_32x32x16_bf16(g1, av, acc1, 0, 0, 0);
    }

    float* Ob = Out + (size_t)b * 256 * 4096 + n0 + wn * 32 + l31;
    #pragma unroll
    for (int r = 0; r < 16; ++r) {
        const int dr = (r & 3) + 8 * (r >> 2) + 4 * hi;
        const int oA = ob + dr, oB = ob + 32 + dr;
        Ob[(size_t)oA * 4096] = acc0[r] * scale[oA] + bias[oA];
        Ob[(size_t)oB * 4096] = acc1[r] * scale[oB] + bias[oB];
    }
}

// ---------------------------------------------------------------------------
extern "C" void kernel_launch(void* const* d_in, const int* in_sizes, int n_in,
                              void* d_out, int out_size, void* d_ws, size_t ws_size,
                              hipStream_t stream)
{
    const float* x        = (const float*)d_in[0];
    const float* upper    = (const float*)d_in[1];
    const float* Wq       = (const float*)d_in[2];
    const float* q_scale  = (const float*)d_in[3];
    const float* q_bias   = (const float*)d_in[4];
    const float* Wkv      = (const float*)d_in[5];
    const float* kv_scale = (const float*)d_in[6];
    const float* kv_bias  = (const float*)d_in[7];
    const float* Wpe      = (const float*)d_in[8];
    const float* pe_scale = (const float*)d_in[9];
    const float* pe_bias  = (const float*)d_in[10];
    const float* Wproj    = (const float*)d_in[11];
    const float* proj_scale = (const float*)d_in[12];
    const float* proj_bias  = (const float*)d_in[13];
    float* out = (float*)d_out;

    ushort* Qb   = (ushort*)d_ws;                           // 8.39 MB
    ushort* Kb   = Qb + (size_t)32 * 4096 * 32;             // 2.10 MB
    ushort* Vb   = Kb + (size_t)32 * 1024 * 32;             // 2.10 MB
    ushort* ao   = Vb + (size_t)32 * 1024 * 32;             // 8.39 MB bf16 [b][256][4096]
    ushort* vh   = ao + (size_t)Bq * DIM * Nq;              // 2.10 MB bf16 [b][256][32*32]
    ushort* Wqb  = vh + (size_t)Bq * DIM * Nu;              // 128 KB
    ushort* Wkvb = Wqb + 256 * 256;                         // 256 KB
    ushort* Wph  = Wkvb + 512 * 256;                        // 128 KB
    ushort* Wpl  = Wph + 256 * 256;                         // 128 KB

    const float qmult = 0.17677669529663687f * 1.4426950408889634f; // qscale*log2e

    prepro<<<dim3(512), 256, 0, stream>>>(Wq, Wqb, Wkv, Wkvb, Wproj, Wph, Wpl);

    qkv_mfma<<<dim3(768), 256, 0, stream>>>(Wqb, x, q_scale, q_bias, qmult,
                                            Wkvb, upper, kv_scale, kv_bias,
                                            Qb, Kb, Vb);

    attn_dw<<<dim3(2048), 256, 0, stream>>>(Qb, Kb, Vb, ao,
                                            Wpe, pe_scale, pe_bias, vh);

    proj_mfma<<<dim3(64, 1, 4), 512, 0, stream>>>(Wph, Wpl, ao, vh,
                                                  proj_scale, proj_bias, out);
}

// Round 14
// 78.704 us; speedup vs baseline: 1.4373x; 1.4373x over previous
//
#include <hip/hip_runtime.h>
#include <hip/hip_bf16.h>

#define DIM 256
#define NHEADS 8
#define HDIM 32
#define Bq 4
#define Nq 4096   // 64*64
#define Nu 1024   // 32*32

typedef __attribute__((ext_vector_type(8))) short bf16x8;
typedef __attribute__((ext_vector_type(16))) float f32x16;
typedef __attribute__((ext_vector_type(4))) unsigned short us4;

__device__ __forceinline__ ushort f2bf(float x) {
    union { float f; unsigned u; } v; v.f = x;
    unsigned r = v.u + 0x7fffu + ((v.u >> 16) & 1u);
    return (ushort)(r >> 16);
}
__device__ __forceinline__ float bf2f(ushort u) {
    union { unsigned u; float f; } v; v.u = ((unsigned)u) << 16;
    return v.f;
}
__device__ __forceinline__ float bfu2f(unsigned lo16shifted) {
    union { unsigned u; float f; } v; v.u = lo16shifted;
    return v.f;
}

// ---------------------------------------------------------------------------
// prepro: weight casts only.  grid 512 x 256 threads.
// ---------------------------------------------------------------------------
__global__ __launch_bounds__(256) void prepro(
    const float* __restrict__ Wq, ushort* __restrict__ Oq,
    const float* __restrict__ Wkv, ushort* __restrict__ Okv,
    const float* __restrict__ Wp, ushort* __restrict__ Oph, ushort* __restrict__ Opl)
{
    const int i = blockIdx.x * 256 + threadIdx.x;
    if (i < 65536) {
        Oq[i] = f2bf(Wq[i]);
        float w = Wp[i];
        ushort h = f2bf(w);
        Oph[i] = h;
        Opl[i] = f2bf(w - bf2f(h));
    }
    Okv[i] = f2bf(Wkv[i]);
}

// ---------------------------------------------------------------------------
// qkv (fused transpose + GEMM): blocks [0,512): Q (128 n-blocks x 4 b);
// [512,768): KV (32 n x 2 oh x 4 b).
// Stages a [32 n][256 c] bf16 tile of fp32 input through swizzled LDS
// (in-register cvt_pk transpose), then each wave computes 64 output rows:
// Q: heads 2w,2w+1; KV: head oh*4+w's K (transposed out) + V (direct out).
// ---------------------------------------------------------------------------
__global__ __launch_bounds__(256, 4) void qkv_mfma(
    const ushort* __restrict__ Wqb, const float* __restrict__ x,
    const float* __restrict__ q_scale, const float* __restrict__ q_bias, float qmult,
    const ushort* __restrict__ Wkvb, const float* __restrict__ upper,
    const float* __restrict__ kv_scale, const float* __restrict__ kv_bias,
    ushort* __restrict__ Qb, ushort* __restrict__ Kb, ushort* __restrict__ Vb)
{
    __shared__ __align__(16) ushort S[32 * 256];   // 16 KB, swizzled [n][c]
    const int id = blockIdx.x;
    const int tid = threadIdx.x;

    const float* In; int N, n0, b, oh; bool isQ;
    if (id < 512) {
        isQ = true; In = x; N = 4096;
        n0 = (id & 127) * 32; b = id >> 7; oh = 0;
    } else {
        int q = id - 512;
        isQ = false; In = upper; N = 1024;
        n0 = (q & 31) * 32; oh = (q >> 5) & 1; b = q >> 6;
    }

    // ---- stage S[n][c] = bf16(In[c][n]) ----
    {
        const int n4 = (tid & 7) * 4, c8 = (tid >> 3) * 8;
        const float* ip = In + ((size_t)b * 256 + c8) * N + n0 + n4;
        unsigned ow[4][4];                 // [local n j][c-pair rp]
        #pragma unroll
        for (int rp = 0; rp < 4; ++rp) {
            float4 f0 = *(const float4*)(ip + (size_t)(2 * rp) * N);
            float4 f1 = *(const float4*)(ip + (size_t)(2 * rp + 1) * N);
            asm("v_cvt_pk_bf16_f32 %0, %1, %2" : "=v"(ow[0][rp]) : "v"(f0.x), "v"(f1.x));
            asm("v_cvt_pk_bf16_f32 %0, %1, %2" : "=v"(ow[1][rp]) : "v"(f0.y), "v"(f1.y));
            asm("v_cvt_pk_bf16_f32 %0, %1, %2" : "=v"(ow[2][rp]) : "v"(f0.z), "v"(f1.z));
            asm("v_cvt_pk_bf16_f32 %0, %1, %2" : "=v"(ow[3][rp]) : "v"(f0.w), "v"(f1.w));
        }
        #pragma unroll
        for (int j = 0; j < 4; ++j) {
            const int n = n4 + j;
            const int slot = ((c8 >> 3) ^ (n & 15)) & 31;
            *(uint4*)(&S[n * 256 + (slot << 3)]) = *(const uint4*)&ow[j][0];
        }
    }
    __syncthreads();

    const int w = tid >> 6, l = tid & 63;
    const int l31 = l & 31, hi = l >> 5;
    const int nsw = l31 & 15;
    const ushort* Srow = &S[l31 * 256];

    if (isQ) {
        const ushort* w0 = Wqb + (size_t)(w * 64 + l31) * 256 + hi * 8;
        const ushort* w1 = w0 + (size_t)32 * 256;
        f32x16 acc0 = {}, acc1 = {};
        #pragma unroll 8
        for (int kk = 0; kk < 256; kk += 16) {
            const int slot = (((kk >> 3) + hi) ^ nsw) & 31;
            bf16x8 av = *(const bf16x8*)(Srow + (slot << 3));
            bf16x8 h0 = *(const bf16x8*)(w0 + kk);
            bf16x8 h1 = *(const bf16x8*)(w1 + kk);
            acc0 = __builtin_amdgcn_mfma_f32_32x32x16_bf16(av, h0, acc0, 0, 0, 0);
            acc1 = __builtin_amdgcn_mfma_f32_32x32x16_bf16(av, h1, acc1, 0, 0, 0);
        }
        #pragma unroll
        for (int t = 0; t < 2; ++t) {
            const f32x16 a = t ? acc1 : acc0;
            const int orow = w * 64 + t * 32 + l31;
            const float sc = q_scale[orow] * qmult;
            const float bi = q_bias[orow] * qmult;
            const int bh = b * 8 + 2 * w + t;
            ushort* Oa = Qb + ((size_t)bh * 4096) * 32 + l31;
            #pragma unroll
            for (int r = 0; r < 16; ++r) {
                const int dn = (r & 3) + 8 * (r >> 2) + 4 * hi;
                Oa[(size_t)(n0 + dn) * 32] = f2bf(a[r] * sc + bi);
            }
        }
    } else {
        const int h = oh * 4 + w;
        const ushort* wk = Wkvb + (size_t)(h * 64 + l31) * 256 + hi * 8;
        const ushort* wv = wk + (size_t)32 * 256;
        f32x16 accK = {}, accV = {};
        #pragma unroll 8
        for (int kk = 0; kk < 256; kk += 16) {
            const int slot = (((kk >> 3) + hi) ^ nsw) & 31;
            bf16x8 av = *(const bf16x8*)(Srow + (slot << 3));
            bf16x8 k0 = *(const bf16x8*)(wk + kk);
            bf16x8 v0 = *(const bf16x8*)(wv + kk);
            accK = __builtin_amdgcn_mfma_f32_32x32x16_bf16(av, k0, accK, 0, 0, 0);
            accV = __builtin_amdgcn_mfma_f32_32x32x16_bf16(v0, av, accV, 0, 0, 0);
        }
        const int bh = b * 8 + h;
        {
            const float sc = kv_scale[h * 64 + l31];
            const float bi = kv_bias[h * 64 + l31];
            ushort* Oa = Kb + ((size_t)bh * 1024) * 32 + l31;
            #pragma unroll
            for (int r = 0; r < 16; ++r) {
                const int dn = (r & 3) + 8 * (r >> 2) + 4 * hi;
                Oa[(size_t)(n0 + dn) * 32] = f2bf(accK[r] * sc + bi);
            }
        }
        {
            ushort* Ob = Vb + (size_t)bh * 32 * 1024;
            #pragma unroll
            for (int r = 0; r < 16; ++r) {
                const int dr = (r & 3) + 8 * (r >> 2) + 4 * hi;
                const float sc = kv_scale[h * 64 + 32 + dr];
                const float bi = kv_bias[h * 64 + 32 + dr];
                Ob[(size_t)dr * 1024 + n0 + l31] = f2bf(accV[r] * sc + bi);
            }
        }
    }
}

// ---------------------------------------------------------------------------
// attn_dw (merged): blocks [0,1024): flash attention (bf16 output);
// [1024,2048): depthwise 7x7 -> 32x32 bf16 field (upsample lives in proj).
// __launch_bounds__(256, 4): do NOT raise — (256,8) capped VGPR at 64,
// compiler spilled (32 VGPR + 121 MB scratch writes/dispatch, R13: +34 µs).
// FROZEN: attention inner loop is the R6-proven structure — do not modify.
// NOTE: do NOT parity-interleave the two halves — blockIdx%8 maps to XCDs
// (R11: +11.6 µs).
// ---------------------------------------------------------------------------
__global__ __launch_bounds__(256, 4) void attn_dw(
    const ushort* __restrict__ Qb, const ushort* __restrict__ Kt,
    const ushort* __restrict__ Vb, ushort* __restrict__ ao,
    const float* __restrict__ Wpe, const float* __restrict__ pe_scale,
    const float* __restrict__ pe_bias, ushort* __restrict__ vh)
{
    __shared__ __align__(16) unsigned char smem[16384];
    const int tid = threadIdx.x;

    if (blockIdx.x < 1024) {
        // ---- attention ----
        const int w = tid >> 6, l = tid & 63;
        const int l31 = l & 31, hi = l >> 5;
        const int lid = blockIdx.x;
        const int j = lid >> 3;
        const int bh = (lid & 7) * 4 + (j >> 5);
        const int qbase = (j & 31) * 128 + w * 32;

        unsigned char (*ldsbuf)[8192] = (unsigned char(*)[8192])smem;

        const ushort* Qp = Qb + ((size_t)bh * 4096 + qbase) * 32;
        const unsigned char* Kg = (const unsigned char*)(Kt + (size_t)bh * 1024 * 32);
        const unsigned char* Vg = (const unsigned char*)(Vb + (size_t)bh * 32 * 1024);

        const bf16x8 qb0 = *(const bf16x8*)(Qp + (size_t)l31 * 32 + hi * 8);
        const bf16x8 qb1 = *(const bf16x8*)(Qp + (size_t)l31 * 32 + 16 + hi * 8);

        const int kr = tid >> 2, kc = tid & 3;
        const int vd = tid >> 3, vc = tid & 7;
        const int kwr = (kr * 64 + kc * 16) ^ ((kr & 7) << 4);
        const int vwr = vd * 128 + ((vc ^ (vd & 7)) << 4);

        f32x16 acc = {};
        float l_run = 0.f;

        uint4 kreg = *(const uint4*)(Kg + kr * 64 + kc * 16);
        uint4 vreg = *(const uint4*)(Vg + vd * 2048 + vc * 16);
        *(uint4*)(&ldsbuf[0][kwr]) = kreg;
        *(uint4*)(&ldsbuf[0][4096 + vwr]) = vreg;
        __syncthreads();

        for (int ph = 0; ph < 16; ++ph) {
            const int cur = ph & 1;
            if (ph < 15) {
                const size_t koff = (size_t)(ph + 1) * 4096;
                const int    voff = (ph + 1) * 128;
                kreg = *(const uint4*)(Kg + koff + kr * 64 + kc * 16);
                vreg = *(const uint4*)(Vg + (size_t)vd * 2048 + voff + vc * 16);
            }
            const unsigned char* Kl = &ldsbuf[cur][0];
            const unsigned char* Vl = &ldsbuf[cur][4096];

            #pragma unroll
            for (int s = 0; s < 2; ++s) {
                const int r = s * 32 + l31;
                bf16x8 ka0 = *(const bf16x8*)(Kl + ((r * 64 + hi * 16) ^ ((r & 7) << 4)));
                bf16x8 ka1 = *(const bf16x8*)(Kl + ((r * 64 + 32 + hi * 16) ^ ((r & 7) << 4)));
                bf16x8 va0 = *(const bf16x8*)(Vl + l31 * 128 + (((s * 4 + hi)     ^ (l31 & 7)) << 4));
                bf16x8 va1 = *(const bf16x8*)(Vl + l31 * 128 + (((s * 4 + 2 + hi) ^ (l31 & 7)) << 4));

                f32x16 sv = {};
                sv = __builtin_amdgcn_mfma_f32_32x32x16_bf16(ka0, qb0, sv, 0, 0, 0);
                sv = __builtin_amdgcn_mfma_f32_32x32x16_bf16(ka1, qb1, sv, 0, 0, 0);

                float p[16];
                #pragma unroll
                for (int r2 = 0; r2 < 16; ++r2) p[r2] = __builtin_amdgcn_exp2f(sv[r2]);
                l_run += (((p[0] + p[1]) + (p[2] + p[3])) + ((p[4] + p[5]) + (p[6] + p[7])))
                       + (((p[8] + p[9]) + (p[10] + p[11])) + ((p[12] + p[13]) + (p[14] + p[15])));

                int c[8];
                #pragma unroll
                for (int i = 0; i < 8; ++i)
                    asm("v_cvt_pk_bf16_f32 %0, %1, %2" : "=v"(c[i]) : "v"(p[2 * i]), "v"(p[2 * i + 1]));
                asm("v_permlane32_swap_b32 %0, %1" : "+v"(c[0]), "+v"(c[2]));
                asm("v_permlane32_swap_b32 %0, %1" : "+v"(c[1]), "+v"(c[3]));
                asm("v_permlane32_swap_b32 %0, %1" : "+v"(c[4]), "+v"(c[6]));
                asm("v_permlane32_swap_b32 %0, %1" : "+v"(c[5]), "+v"(c[7]));

                union { int i[4]; bf16x8 v; } b0u, b1u;
                b0u.i[0] = c[0]; b0u.i[1] = c[1]; b0u.i[2] = c[2]; b0u.i[3] = c[3];
                b1u.i[0] = c[4]; b1u.i[1] = c[5]; b1u.i[2] = c[6]; b1u.i[3] = c[7];

                acc = __builtin_amdgcn_mfma_f32_32x32x16_bf16(va0, b0u.v, acc, 0, 0, 0);
                acc = __builtin_amdgcn_mfma_f32_32x32x16_bf16(va1, b1u.v, acc, 0, 0, 0);
            }

            if (ph < 15) {
                const int nxt = cur ^ 1;
                *(uint4*)(&ldsbuf[nxt][kwr]) = kreg;
                *(uint4*)(&ldsbuf[nxt][4096 + vwr]) = vreg;
            }
            __syncthreads();
        }

        l_run += __shfl_xor(l_run, 32);
        float inv = 1.0f / l_run;

        ushort* aob = ao + ((size_t)(bh >> 3) * 256 + (bh & 7) * 32) * 4096 + qbase + l31;
        #pragma unroll
        for (int r = 0; r < 16; ++r) {
            const int d = (r & 3) + 8 * (r >> 2) + 4 * hi;
            aob[(size_t)d * 4096] = f2bf(acc[r] * inv);
        }
    } else {
        // ---- depthwise 7x7 (32x32 bf16 output; upsample in proj) ----
        const int bc = blockIdx.x - 1024;
        const int b = bc >> 8, c = bc & 255;
        const ushort* vp = Vb + ((size_t)(b * 8 + (c >> 5)) * 32 + (c & 31)) * 1024;

        float* t  = (float*)smem;               // 38*38*4 = 5776 B
        float* wl = (float*)(smem + 5776);      // 196 B

        for (int i = tid; i < 38 * 38; i += 256) {
            int yy = i / 38 - 3, xx = i % 38 - 3;
            t[i] = (yy >= 0 && yy < 32 && xx >= 0 && xx < 32) ? bf2f(vp[yy * 32 + xx]) : 0.f;
        }
        if (tid < 49) wl[tid] = Wpe[(size_t)c * 49 + tid];
        __syncthreads();

        const float sc = pe_scale[c], bi = pe_bias[c];
        ushort* op = vh + (size_t)bc * 1024;
        for (int i = tid; i < 1024; i += 256) {
            int y = i >> 5, x = i & 31;
            float s = 0.f;
            #pragma unroll
            for (int ky = 0; ky < 7; ++ky)
                #pragma unroll
                for (int kx = 0; kx < 7; ++kx)
                    s += t[(y + ky) * 38 + x + kx] * wl[ky * 7 + kx];
            op[i] = f2bf(s * sc + bi);
        }
    }
}

// ---------------------------------------------------------------------------
// Output projection (fused transpose+add+bilinear-upsample): 512-thread
// blocks, each covering ALL o=256 for one 64-wide n-tile (= one output row
// y = blockIdx.x).  Staging computes S[n][c] = ao[c][n] + bilinear(vh[c])
// inline (fx in {0.75,0.25} by x parity; fy uniform per block); vh is the
// bf16 32x32 pre-upsample field (unpacked to f32, lerped exactly).
// 8 waves: wave w -> o-quarter (w&3)*64, n-half (w>>2)*32.
// ---------------------------------------------------------------------------
__global__ __launch_bounds__(512, 2) void proj_mfma(
    const ushort* __restrict__ Whi, const ushort* __restrict__ Wlo,
    const ushort* __restrict__ ao, const ushort* __restrict__ vh,
    const float* __restrict__ scale, const float* __restrict__ bias,
    float* __restrict__ Out)
{
    __shared__ __align__(16) ushort S[64 * 256];   // 32 KB, swizzled [n][c]
    const int tid = threadIdx.x;
    const int b  = blockIdx.z;
    const int y  = blockIdx.x;             // output row; n0 = y*64
    const int n0 = y * 64;

    // ---- stage S[n][c] = ao[c][n] + vpe_bilinear(c, y, x=n-n0) ----
    {
        const int m  = tid & 15;           // x-quad: x = 4m + j, j=0..3
        const int c8 = (tid >> 4) * 8;     // 8 channels

        const int y0  = (y - 1) >> 1;
        const float fy = (y & 1) ? 0.25f : 0.75f;
        const float gy = 1.0f - fy;
        const int y0c = max(y0, 0), y1c = min(y0 + 1, 31);
        const int aIdx = max(m - 1, 0), cIdx = min(m + 1, 15);

        float sval[4][8];                  // [j][cc]
        #pragma unroll
        for (int cc = 0; cc < 8; ++cc) {
            const int ch = c8 + cc;
            const ushort* rowb = vh + (size_t)(b * 256 + ch) * 1024;
            const ushort* rT = rowb + y0c * 32;
            const ushort* rB = rowb + y1c * 32;
            // 2 bf16 per u32 load (4B aligned: even ushort indices)
            const unsigned ta  = *(const unsigned*)(rT + 2 * aIdx);
            const unsigned tb  = *(const unsigned*)(rT + 2 * m);
            const unsigned tc  = *(const unsigned*)(rT + 2 * cIdx);
            const unsigned ba  = *(const unsigned*)(rB + 2 * aIdx);
            const unsigned bb  = *(const unsigned*)(rB + 2 * m);
            const unsigned bc2 = *(const unsigned*)(rB + 2 * cIdx);
            const float tbx = bfu2f(tb << 16), tby = bfu2f(tb & 0xffff0000u);
            const float bbx = bfu2f(bb << 16), bby = bfu2f(bb & 0xffff0000u);
            const float t_m1 = (m == 0)  ? tbx : bfu2f(ta & 0xffff0000u); // pos 2m-1
            const float t_p2 = (m == 15) ? tby : bfu2f(tc << 16);         // pos 2m+2
            const float b_m1 = (m == 0)  ? bbx : bfu2f(ba & 0xffff0000u);
            const float b_p2 = (m == 15) ? bby : bfu2f(bc2 << 16);
            // horizontal lerps: j=0 fx=.75 (x0=2m-1), j=1 fx=.25 (x0=2m),
            // j=2 fx=.75 (x0=2m), j=3 fx=.25 (x0=2m+1)
            const float ht0 = 0.25f * t_m1 + 0.75f * tbx;
            const float ht1 = 0.75f * tbx + 0.25f * tby;
            const float ht2 = 0.25f * tbx + 0.75f * tby;
            const float ht3 = 0.75f * tby + 0.25f * t_p2;
            const float hb0 = 0.25f * b_m1 + 0.75f * bbx;
            const float hb1 = 0.75f * bbx + 0.25f * bby;
            const float hb2 = 0.25f * bbx + 0.75f * bby;
            const float hb3 = 0.75f * bby + 0.25f * b_p2;

            const ushort* ap = ao + (size_t)(b * 256 + ch) * 4096 + n0 + m * 4;
            uint2 av = *(const uint2*)ap;
            const float a0 = bfu2f(av.x << 16);
            const float a1 = bfu2f(av.x & 0xffff0000u);
            const float a2 = bfu2f(av.y << 16);
            const float a3 = bfu2f(av.y & 0xffff0000u);

            sval[0][cc] = a0 + (gy * ht0 + fy * hb0);
            sval[1][cc] = a1 + (gy * ht1 + fy * hb1);
            sval[2][cc] = a2 + (gy * ht2 + fy * hb2);
            sval[3][cc] = a3 + (gy * ht3 + fy * hb3);
        }

        #pragma unroll
        for (int j = 0; j < 4; ++j) {
            unsigned ow[4];
            #pragma unroll
            for (int rp = 0; rp < 4; ++rp)
                asm("v_cvt_pk_bf16_f32 %0, %1, %2"
                    : "=v"(ow[rp]) : "v"(sval[j][2 * rp]), "v"(sval[j][2 * rp + 1]));
            const int n = m * 4 + j;
            const int slot = (((c8 >> 3) ^ (n & 15)) & 31);
            *(uint4*)(&S[n * 256 + (slot << 3)]) = *(const uint4*)&ow[0];
        }
    }
    __syncthreads();

    // ---- GEMM ----
    const int w = tid >> 6, l = tid & 63;
    const int l31 = l & 31, hi = l >> 5;
    const int wo = w & 3, wn = w >> 2;     // o-quarter (64), n-half (32)
    const int ob = wo * 64;

    const ushort* wh0 = Whi + (size_t)(ob + l31) * 256 + hi * 8;
    const ushort* wh1 = wh0 + (size_t)32 * 256;
    const ushort* wl0 = Wlo + (size_t)(ob + l31) * 256 + hi * 8;
    const ushort* wl1 = wl0 + (size_t)32 * 256;

    const int nloc = wn * 32 + l31;
    const ushort* Srow = &S[nloc * 256];
    const int nsw = nloc & 15;

    f32x16 acc0 = {}, acc1 = {};           // acc0: o in [ob,ob+32), acc1: +32
    #pragma unroll 4
    for (int kk = 0; kk < 256; kk += 16) {
        const int slot = (((kk >> 3) + hi) ^ nsw) & 31;
        bf16x8 av = *(const bf16x8*)(Srow + (slot << 3));
        bf16x8 h0 = *(const bf16x8*)(wh0 + kk);
        bf16x8 h1 = *(const bf16x8*)(wh1 + kk);
        bf16x8 g0 = *(const bf16x8*)(wl0 + kk);
        bf16x8 g1 = *(const bf16x8*)(wl1 + kk);
        acc0 = __builtin_amdgcn_mfma_f32_32x32x16_bf16(h0, av, acc0, 0, 0, 0);
        acc1 = __builtin_amdgcn_mfma_f32_32x32x16_bf16(h1, av, acc1, 0, 0, 0);
        acc0 = __builtin_amdgcn_mfma_f32_32x32x16_bf16(g0, av, acc0, 0, 0, 0);
        acc1 = __builtin_amdgcn_mfma_f32_32x32x16_bf16(g1, av, acc1, 0, 0, 0);
    }

    float* Ob = Out + (size_t)b * 256 * 4096 + n0 + wn * 32 + l31;
    #pragma unroll
    for (int r = 0; r < 16; ++r) {
        const int dr = (r & 3) + 8 * (r >> 2) + 4 * hi;
        const int oA = ob + dr, oB = ob + 32 + dr;
        Ob[(size_t)oA * 4096] = acc0[r] * scale[oA] + bias[oA];
        Ob[(size_t)oB * 4096] = acc1[r] * scale[oB] + bias[oB];
    }
}

// ---------------------------------------------------------------------------
extern "C" void kernel_launch(void* const* d_in, const int* in_sizes, int n_in,
                              void* d_out, int out_size, void* d_ws, size_t ws_size,
                              hipStream_t stream)
{
    const float* x        = (const float*)d_in[0];
    const float* upper    = (const float*)d_in[1];
    const float* Wq       = (const float*)d_in[2];
    const float* q_scale  = (const float*)d_in[3];
    const float* q_bias   = (const float*)d_in[4];
    const float* Wkv      = (const float*)d_in[5];
    const float* kv_scale = (const float*)d_in[6];
    const float* kv_bias  = (const float*)d_in[7];
    const float* Wpe      = (const float*)d_in[8];
    const float* pe_scale = (const float*)d_in[9];
    const float* pe_bias  = (const float*)d_in[10];
    const float* Wproj    = (const float*)d_in[11];
    const float* proj_scale = (const float*)d_in[12];
    const float* proj_bias  = (const float*)d_in[13];
    float* out = (float*)d_out;

    ushort* Qb   = (ushort*)d_ws;                           // 8.39 MB
    ushort* Kb   = Qb + (size_t)32 * 4096 * 32;             // 2.10 MB
    ushort* Vb   = Kb + (size_t)32 * 1024 * 32;             // 2.10 MB
    ushort* ao   = Vb + (size_t)32 * 1024 * 32;             // 8.39 MB bf16 [b][256][4096]
    ushort* vh   = ao + (size_t)Bq * DIM * Nq;              // 2.10 MB bf16 [b][256][32*32]
    ushort* Wqb  = vh + (size_t)Bq * DIM * Nu;              // 128 KB
    ushort* Wkvb = Wqb + 256 * 256;                         // 256 KB
    ushort* Wph  = Wkvb + 512 * 256;                        // 128 KB
    ushort* Wpl  = Wph + 256 * 256;                         // 128 KB

    const float qmult = 0.17677669529663687f * 1.4426950408889634f; // qscale*log2e

    prepro<<<dim3(512), 256, 0, stream>>>(Wq, Wqb, Wkv, Wkvb, Wproj, Wph, Wpl);

    qkv_mfma<<<dim3(768), 256, 0, stream>>>(Wqb, x, q_scale, q_bias, qmult,
                                            Wkvb, upper, kv_scale, kv_bias,
                                            Qb, Kb, Vb);

    attn_dw<<<dim3(2048), 256, 0, stream>>>(Qb, Kb, Vb, ao,
                                            Wpe, pe_scale, pe_bias, vh);

    proj_mfma<<<dim3(64, 1, 4), 512, 0, stream>>>(Wph, Wpl, ao, vh,
                                                  proj_scale, proj_bias, out);
}